// Round 1
// baseline (136.405 us; speedup 1.0000x reference)
//
#include <hip/hip_runtime.h>
#include <hip/hip_bf16.h>

// NT-Xent (SimCLR) fused loss, MI355X gfx950.
// Pipeline: normalize(fp32->bf16) -> tiled bf16 MFMA Gram + fused exp/row-sum
//           (atomicAdd into S[N], partner logit into pos[N]) -> final reduce.
//
// ws layout: [S: N floats][pos: N floats][zn: N*D bf16]

#define N_TOT 8192
#define BATCH 4096
#define DIM   256
#define BK    64

typedef short bf16x8 __attribute__((ext_vector_type(8)));
typedef float f32x4  __attribute__((ext_vector_type(4)));

__device__ __forceinline__ void load_lds16(const void* g, void* l) {
  // async global->LDS, 16B/lane; LDS dest is wave-uniform base + lane*16
  __builtin_amdgcn_global_load_lds(
      (const __attribute__((address_space(1))) unsigned int*)g,
      (__attribute__((address_space(3))) unsigned int*)l,
      16, 0, 0);
}

__device__ __forceinline__ unsigned short f32_to_bf16(float f) {
  unsigned int u = __float_as_uint(f);
  u += 0x7fff + ((u >> 16) & 1);   // RNE
  return (unsigned short)(u >> 16);
}

// One wave per row: 64 lanes x float4 = 256 elements. Also zeros S.
__global__ __launch_bounds__(256) void normalize_kernel(
    const float* __restrict__ z, unsigned short* __restrict__ zn,
    float* __restrict__ S) {
  const int wave = threadIdx.x >> 6;
  const int lane = threadIdx.x & 63;
  const int row  = blockIdx.x * 4 + wave;
  float4 v = ((const float4*)(z + (size_t)row * DIM))[lane];
  float ss = v.x * v.x + v.y * v.y + v.z * v.z + v.w * v.w;
#pragma unroll
  for (int m = 1; m <= 32; m <<= 1) ss += __shfl_xor(ss, m);
  float inv = 1.0f / sqrtf(ss);
  ushort4 o;
  o.x = f32_to_bf16(v.x * inv);
  o.y = f32_to_bf16(v.y * inv);
  o.z = f32_to_bf16(v.z * inv);
  o.w = f32_to_bf16(v.w * inv);
  ((ushort4*)(zn + (size_t)row * DIM))[lane] = o;
  if (threadIdx.x < 4) S[blockIdx.x * 4 + threadIdx.x] = 0.0f;
}

// 128x128 tile of sim = zn * zn^T * 10, fused exp + per-row sum.
// blockIdx.y = row tile (rb), blockIdx.x = col tile (cb).
// 4 waves, each owns a 64x64 quadrant = 4x4 fragments of 16x16x32 bf16 MFMA.
__global__ __launch_bounds__(256, 2) void simclr_tile_kernel(
    const unsigned short* __restrict__ zn, float* __restrict__ S,
    float* __restrict__ pos) {
  const int rb = blockIdx.y, cb = blockIdx.x;
  const int tid = threadIdx.x;
  const int wave = tid >> 6, lane = tid & 63;
  const int wm = wave >> 1, wn = wave & 1;      // wave quadrant (2x2)
  const int c = lane & 15, quad = lane >> 4;    // MFMA lane coords

  // LDS: row-major [128][BK] bf16, 16KB each. XOR chunk swizzle:
  // slot (r, s) holds global chunk s ^ (r&7) (chunk = 8 bf16 = 16B).
  __shared__ alignas(16) unsigned short As[128 * BK];
  __shared__ alignas(16) unsigned short Bs[128 * BK];

  f32x4 acc[4][4];
#pragma unroll
  for (int i = 0; i < 4; ++i)
#pragma unroll
    for (int j = 0; j < 4; ++j) acc[i][j] = (f32x4){0.f, 0.f, 0.f, 0.f};

  // Staging geometry: per issue, a wave writes 8 rows x 64 bf16 = 1024B,
  // lane l -> row +(l>>3), LDS chunk (l&7); fetches global chunk (l&7)^(l>>3).
  const int srow   = lane >> 3;                       // 0..7
  const int schunk = (lane & 7) ^ srow;               // swizzled global chunk
  const size_t a_row0 = (size_t)rb * 128;
  const size_t b_row0 = (size_t)cb * 128;

#pragma unroll
  for (int kb = 0; kb < DIM / BK; ++kb) {
#pragma unroll
    for (int t = 0; t < 4; ++t) {
      const int rloc = wave * 32 + t * 8 + srow;      // row within tile
      const unsigned short* ga =
          zn + (a_row0 + rloc) * DIM + kb * BK + schunk * 8;
      const unsigned short* gb =
          zn + (b_row0 + rloc) * DIM + kb * BK + schunk * 8;
      load_lds16(ga, As + rloc * BK + (lane & 7) * 8);
      load_lds16(gb, Bs + rloc * BK + (lane & 7) * 8);
    }
    __syncthreads();

#pragma unroll
    for (int kk = 0; kk < BK / 32; ++kk) {
      const int kc = kk * 4 + quad;                   // 16B chunk index in row
      const int sl = (kc ^ (c & 7)) * 8;              // de-swizzled elem offset
      bf16x8 af[4], bfr[4];
#pragma unroll
      for (int f = 0; f < 4; ++f) {
        af[f]  = *(const bf16x8*)(As + (wm * 64 + f * 16 + c) * BK + sl);
        bfr[f] = *(const bf16x8*)(Bs + (wn * 64 + f * 16 + c) * BK + sl);
      }
#pragma unroll
      for (int fm = 0; fm < 4; ++fm)
#pragma unroll
        for (int fn = 0; fn < 4; ++fn)
          acc[fm][fn] = __builtin_amdgcn_mfma_f32_16x16x32_bf16(
              af[fm], bfr[fn], acc[fm][fn], 0, 0, 0);
    }
    __syncthreads();
  }

  // Epilogue: logits = acc*10; exp; skip diag; capture partner; row-reduce.
  // C/D layout: row = quad*4 + reg, col = lane&15 within each 16x16 frag.
#pragma unroll
  for (int fm = 0; fm < 4; ++fm) {
#pragma unroll
    for (int r = 0; r < 4; ++r) {
      const int grow = rb * 128 + wm * 64 + fm * 16 + quad * 4 + r;
      float s = 0.f;
#pragma unroll
      for (int fn = 0; fn < 4; ++fn) {
        const int gcol = cb * 128 + wn * 64 + fn * 16 + c;
        const float logit = acc[fm][fn][r] * 10.0f;
        float e = __expf(logit);
        if (gcol == grow) e = 0.f;                    // exclude self-sim
        if (gcol == (grow ^ BATCH)) pos[grow] = logit; // partner (i <-> i+B)
        s += e;
      }
      // reduce across the 16 column-lanes of this row
      s += __shfl_xor(s, 1);
      s += __shfl_xor(s, 2);
      s += __shfl_xor(s, 4);
      s += __shfl_xor(s, 8);
      if (c == 0) atomicAdd(&S[grow], s);
    }
  }
}

// loss = mean(log(S_i) - pos_i)
__global__ __launch_bounds__(1024) void finalize_kernel(
    const float* __restrict__ S, const float* __restrict__ pos,
    float* __restrict__ out) {
  const int tid = threadIdx.x;
  float a = 0.f;
  for (int i = tid; i < N_TOT; i += 1024) a += logf(S[i]) - pos[i];
#pragma unroll
  for (int m = 1; m <= 32; m <<= 1) a += __shfl_xor(a, m);
  __shared__ float red[16];
  if ((tid & 63) == 0) red[tid >> 6] = a;
  __syncthreads();
  if (tid < 16) {
    float v = red[tid];
    v += __shfl_xor(v, 1);
    v += __shfl_xor(v, 2);
    v += __shfl_xor(v, 4);
    v += __shfl_xor(v, 8);
    if (tid == 0) out[0] = v * (1.0f / (float)N_TOT);
  }
}

extern "C" void kernel_launch(void* const* d_in, const int* in_sizes, int n_in,
                              void* d_out, int out_size, void* d_ws,
                              size_t ws_size, hipStream_t stream) {
  const float* z = (const float*)d_in[0];
  float* out = (float*)d_out;
  char* ws = (char*)d_ws;
  float* S = (float*)ws;                                   // N floats
  float* pos = (float*)(ws + N_TOT * sizeof(float));       // N floats
  unsigned short* zn =
      (unsigned short*)(ws + 2 * N_TOT * sizeof(float));   // N*D bf16

  normalize_kernel<<<N_TOT / 4, 256, 0, stream>>>(z, zn, S);
  dim3 grid(N_TOT / 128, N_TOT / 128);
  simclr_tile_kernel<<<grid, 256, 0, stream>>>(zn, S, pos);
  finalize_kernel<<<1, 1024, 0, stream>>>(S, pos, out);
}